// Round 1
// baseline (480.320 us; speedup 1.0000x reference)
//
#include <hip/hip_runtime.h>
#include <hip/hip_bf16.h>
#include <math.h>

typedef __bf16 bf16x8 __attribute__((ext_vector_type(8)));
typedef __bf16 bf16x4 __attribute__((ext_vector_type(4)));
typedef float  f32x4  __attribute__((ext_vector_type(4)));

#define MFMA16(a, b, c) __builtin_amdgcn_mfma_f32_16x16x32_bf16((a), (b), (c), 0, 0, 0)

// async global->LDS, 16B per lane. LDS dest must be wave-uniform base + lane*16.
__device__ __forceinline__ void gl16(const void* g, void* l) {
  __builtin_amdgcn_global_load_lds(
      (const __attribute__((address_space(1))) unsigned int*)g,
      (__attribute__((address_space(3))) unsigned int*)l, 16, 0, 0);
}

// ---------------------------------------------------------------------------
// fp32 -> bf16 cast, vectorized
// ---------------------------------------------------------------------------
__global__ __launch_bounds__(256) void f32_to_bf16(const float* __restrict__ in,
                                                   __bf16* __restrict__ out, int n) {
  int i = (blockIdx.x * 256 + threadIdx.x) * 4;
  if (i < n) {
    float4 f = *(const float4*)(in + i);
    bf16x4 o = {(__bf16)f.x, (__bf16)f.y, (__bf16)f.z, (__bf16)f.w};
    *(bf16x4*)(out + i) = o;
  }
}

// ---------------------------------------------------------------------------
// m97-style bf16 GEMM: C[M,N] = A[M,K] @ B[N,K]^T + bias, fused epilogues.
// 128x128 tile, BK=32, 256 thr (4 waves, 2x2 of 64x64), 16x16x32 MFMA.
// MODE 0: QKV scatter (q scaled 0.125) -> bf16 q/k/v  [h][b][s][d]
// MODE 1/3: outF = resid + gemm + bias (fp32)
// MODE 2: outB = bf16(gelu_exact(gemm + bias))
// ---------------------------------------------------------------------------
template <int MODE>
__global__ __launch_bounds__(256, 2) void gemm_bt(
    const __bf16* __restrict__ A, const __bf16* __restrict__ Bw,
    const float* __restrict__ bias, const float* __restrict__ resid,
    float* __restrict__ outF, __bf16* __restrict__ outB, int M, int N, int K) {
  __shared__ __bf16 As[128 * 32];
  __shared__ __bf16 Bs[128 * 32];
  const int tid = threadIdx.x;
  const int wave = tid >> 6, lane = tid & 63;
  const int quad = lane >> 4, l16 = lane & 15;
  const int wm = (wave >> 1) * 64, wn = (wave & 1) * 64;
  const long bm = (long)blockIdx.y * 128, bn = (long)blockIdx.x * 128;
  const int r0 = tid >> 2;          // staging row (4 threads x 16B cover 64B row)
  const int c0 = (tid & 3) * 8;     // staging col (bf16)
  const __bf16* Ag = A + (bm + r0) * (long)K + c0;
  const __bf16* Bg = Bw + (bn + r0) * (long)K + c0;

  f32x4 acc[4][4] = {};

  for (int k0 = 0; k0 < K; k0 += 32) {
    __syncthreads();
    gl16(Ag + k0, &As[tid * 8]);
    gl16(Ag + 64 * (long)K + k0, &As[2048 + tid * 8]);
    gl16(Bg + k0, &Bs[tid * 8]);
    gl16(Bg + 64 * (long)K + k0, &Bs[2048 + tid * 8]);
    __syncthreads();

    bf16x8 af[4], bfr[4];
#pragma unroll
    for (int mt = 0; mt < 4; mt++)
      af[mt] = *(const bf16x8*)&As[(wm + mt * 16 + l16) * 32 + quad * 8];
#pragma unroll
    for (int nt = 0; nt < 4; nt++)
      bfr[nt] = *(const bf16x8*)&Bs[(wn + nt * 16 + l16) * 32 + quad * 8];
#pragma unroll
    for (int nt = 0; nt < 4; nt++)
#pragma unroll
      for (int mt = 0; mt < 4; mt++)
        acc[mt][nt] = MFMA16(af[mt], bfr[nt], acc[mt][nt]);
  }

#pragma unroll
  for (int mt = 0; mt < 4; mt++) {
#pragma unroll
    for (int nt = 0; nt < 4; nt++) {
#pragma unroll
      for (int r = 0; r < 4; r++) {
        const int row = (int)bm + wm + mt * 16 + quad * 4 + r;
        const int col = (int)bn + wn + nt * 16 + l16;
        float v = acc[mt][nt][r] + bias[col];
        if (MODE == 0) {
          const int b = row >> 11, s = row & 2047;
          const int h = col / 192, rem = col - h * 192;
          const int seg = rem >> 6, d = rem & 63;
          if (seg == 0) v *= 0.125f;  // fold 1/sqrt(HD) into Q
          outB[(long)seg * 4194304 + ((long)((h * 2 + b) * 2048 + s)) * 64 + d] = (__bf16)v;
        } else if (MODE == 2) {
          const float g = 0.5f * v * (1.0f + erff(v * 0.70710678118654752f));
          outB[(long)row * N + col] = (__bf16)g;
        } else {
          const long idx = (long)row * N + col;
          outF[idx] = resid[idx] + v;
        }
      }
    }
  }
}

// ---------------------------------------------------------------------------
// Flash attention: grid (32 q-tiles, 32 hb). Block = 4 waves x 16 q-rows.
// KV tiles of 64 keys. Q pre-scaled by 0.125 in QKV epilogue.
// ---------------------------------------------------------------------------
__global__ __launch_bounds__(256) void flash_attn(const __bf16* __restrict__ Qb,
                                                  const __bf16* __restrict__ Kb,
                                                  const __bf16* __restrict__ Vb,
                                                  __bf16* __restrict__ ctx) {
  __shared__ __bf16 Vt[64 * 72];      // [d][key], stride 72 (16B-aligned rows)
  __shared__ __bf16 Pb[4][16 * 72];   // per-wave P, stride 72
  const int tid = threadIdx.x;
  const int wave = tid >> 6, lane = tid & 63;
  const int quad = lane >> 4, l16 = lane & 15;
  const int hb = blockIdx.y;
  const int h = hb >> 1, b = hb & 1;
  const long base = (long)hb * 2048 * 64;
  const __bf16* Q = Qb + base;
  const __bf16* K = Kb + base;
  const __bf16* V = Vb + base;
  const int qr = blockIdx.x * 64 + wave * 16;

  const bf16x8 q0 = *(const bf16x8*)&Q[(qr + l16) * 64 + quad * 8];
  const bf16x8 q1 = *(const bf16x8*)&Q[(qr + l16) * 64 + 32 + quad * 8];

  f32x4 o[4] = {};
  float mrow[4] = {-1e30f, -1e30f, -1e30f, -1e30f};
  float lrow[4] = {0.f, 0.f, 0.f, 0.f};

  const int vkey = tid >> 2;         // 0..63
  const int vd0 = (tid & 3) * 16;    // 0,16,32,48

  for (int kt = 0; kt < 2048; kt += 64) {
    __syncthreads();  // protect Vt from previous iteration's readers
    {
      bf16x8 v0 = *(const bf16x8*)&V[(kt + vkey) * 64 + vd0];
      bf16x8 v1 = *(const bf16x8*)&V[(kt + vkey) * 64 + vd0 + 8];
#pragma unroll
      for (int j = 0; j < 8; j++) {
        Vt[(vd0 + j) * 72 + vkey] = v0[j];
        Vt[(vd0 + 8 + j) * 72 + vkey] = v1[j];
      }
    }
    __syncthreads();

    // S = Q K^T (C-layout: row = quad*4+r, col = nt*16 + l16)
    f32x4 s[4];
#pragma unroll
    for (int nt = 0; nt < 4; nt++) {
      bf16x8 k0 = *(const bf16x8*)&K[(kt + nt * 16 + l16) * 64 + quad * 8];
      bf16x8 k1 = *(const bf16x8*)&K[(kt + nt * 16 + l16) * 64 + 32 + quad * 8];
      f32x4 z = {};
      z = MFMA16(q0, k0, z);
      z = MFMA16(q1, k1, z);
      s[nt] = z;
    }

    // online softmax (per row; rows live across the 16 lanes of each quad)
    float alpha[4];
#pragma unroll
    for (int r = 0; r < 4; r++) {
      float m0 = fmaxf(fmaxf(s[0][r], s[1][r]), fmaxf(s[2][r], s[3][r]));
      m0 = fmaxf(m0, __shfl_xor(m0, 1));
      m0 = fmaxf(m0, __shfl_xor(m0, 2));
      m0 = fmaxf(m0, __shfl_xor(m0, 4));
      m0 = fmaxf(m0, __shfl_xor(m0, 8));
      const float nm = fmaxf(mrow[r], m0);
      alpha[r] = __expf(mrow[r] - nm);
      mrow[r] = nm;
    }
    float psum[4] = {0.f, 0.f, 0.f, 0.f};
#pragma unroll
    for (int nt = 0; nt < 4; nt++)
#pragma unroll
      for (int r = 0; r < 4; r++) {
        const float p = __expf(s[nt][r] - mrow[r]);
        s[nt][r] = p;
        psum[r] += p;
      }
#pragma unroll
    for (int r = 0; r < 4; r++) {
      float ps = psum[r];
      ps += __shfl_xor(ps, 1);
      ps += __shfl_xor(ps, 2);
      ps += __shfl_xor(ps, 4);
      ps += __shfl_xor(ps, 8);
      lrow[r] = lrow[r] * alpha[r] + ps;
    }
#pragma unroll
    for (int nt = 0; nt < 4; nt++)
#pragma unroll
      for (int r = 0; r < 4; r++)
        o[nt][r] = o[nt][r] * alpha[r];

    // P: C-layout -> LDS -> A-operand layout (wave-private, no barrier needed)
#pragma unroll
    for (int nt = 0; nt < 4; nt++)
#pragma unroll
      for (int r = 0; r < 4; r++)
        Pb[wave][(quad * 4 + r) * 72 + nt * 16 + l16] = (__bf16)s[nt][r];

    const bf16x8 p0 = *(const bf16x8*)&Pb[wave][l16 * 72 + quad * 8];
    const bf16x8 p1 = *(const bf16x8*)&Pb[wave][l16 * 72 + 32 + quad * 8];
#pragma unroll
    for (int nt = 0; nt < 4; nt++) {
      bf16x8 vf0 = *(const bf16x8*)&Vt[(nt * 16 + l16) * 72 + quad * 8];
      bf16x8 vf1 = *(const bf16x8*)&Vt[(nt * 16 + l16) * 72 + 32 + quad * 8];
      o[nt] = MFMA16(p0, vf0, o[nt]);
      o[nt] = MFMA16(p1, vf1, o[nt]);
    }
  }

  // write ctx in [b][s][h*64+d] layout (A of out-proj GEMM)
#pragma unroll
  for (int nt = 0; nt < 4; nt++)
#pragma unroll
    for (int r = 0; r < 4; r++) {
      const int srow = qr + quad * 4 + r;
      const float val = o[nt][r] / lrow[r];
      const int d = nt * 16 + l16;
      ctx[((long)(b * 2048 + srow)) * 1024 + h * 64 + d] = (__bf16)val;
    }
}

// ---------------------------------------------------------------------------
// LayerNorm over rows of 1024 fp32. One block (256 thr) per row.
// ---------------------------------------------------------------------------
template <int WB>
__global__ __launch_bounds__(256) void layernorm_k(const float* __restrict__ in,
                                                   const float* __restrict__ g,
                                                   const float* __restrict__ be,
                                                   float* __restrict__ outF,
                                                   __bf16* __restrict__ outB) {
  const int tid = threadIdx.x;
  const long row = blockIdx.x;
  const float4 v = ((const float4*)(in + row * 1024))[tid];
  float sum = v.x + v.y + v.z + v.w;
  float sq = v.x * v.x + v.y * v.y + v.z * v.z + v.w * v.w;
#pragma unroll
  for (int m = 32; m >= 1; m >>= 1) {
    sum += __shfl_xor(sum, m);
    sq += __shfl_xor(sq, m);
  }
  __shared__ float red[8];
  const int wave = tid >> 6;
  if ((tid & 63) == 0) {
    red[wave] = sum;
    red[4 + wave] = sq;
  }
  __syncthreads();
  sum = red[0] + red[1] + red[2] + red[3];
  sq = red[4] + red[5] + red[6] + red[7];
  const float mu = sum * (1.f / 1024.f);
  const float var = sq * (1.f / 1024.f) - mu * mu;
  const float rs = rsqrtf(var + 1e-5f);
  const float4 gv = ((const float4*)g)[tid];
  const float4 bv = ((const float4*)be)[tid];
  float4 o;
  o.x = (v.x - mu) * rs * gv.x + bv.x;
  o.y = (v.y - mu) * rs * gv.y + bv.y;
  o.z = (v.z - mu) * rs * gv.z + bv.z;
  o.w = (v.w - mu) * rs * gv.w + bv.w;
  ((float4*)(outF + row * 1024))[tid] = o;
  if (WB) {
    bf16x4 ob = {(__bf16)o.x, (__bf16)o.y, (__bf16)o.z, (__bf16)o.w};
    *(bf16x4*)&outB[row * 1024 + tid * 4] = ob;
  }
}

// ---------------------------------------------------------------------------
extern "C" void kernel_launch(void* const* d_in, const int* in_sizes, int n_in,
                              void* d_out, int out_size, void* d_ws, size_t ws_size,
                              hipStream_t stream) {
  const float* x     = (const float*)d_in[0];
  const float* w_qkv = (const float*)d_in[1];
  const float* b_qkv = (const float*)d_in[2];
  const float* w_out = (const float*)d_in[3];
  const float* b_out = (const float*)d_in[4];
  const float* g1    = (const float*)d_in[5];
  const float* be1   = (const float*)d_in[6];
  const float* g2    = (const float*)d_in[7];
  const float* be2   = (const float*)d_in[8];
  const float* w1    = (const float*)d_in[9];
  const float* bf1   = (const float*)d_in[10];
  const float* w2    = (const float*)d_in[11];
  const float* bf2   = (const float*)d_in[12];
  float* out = (float*)d_out;

  // workspace layout (MB offsets), with aliasing: total 88 MB
  char* ws = (char*)d_ws;
  const long MB = 1024L * 1024;
  __bf16* wqkvb = (__bf16*)(ws + 0 * MB);    // 6 MB
  __bf16* woutb = (__bf16*)(ws + 6 * MB);    // 2 MB
  __bf16* w1b   = (__bf16*)(ws + 8 * MB);    // 8 MB
  __bf16* w2b   = (__bf16*)(ws + 16 * MB);   // 8 MB
  __bf16* xb    = (__bf16*)(ws + 24 * MB);   // 8 MB
  __bf16* qkvb  = (__bf16*)(ws + 32 * MB);   // 24 MB (dead after flash)
  __bf16* ctxb  = (__bf16*)(ws + 56 * MB);   // 8 MB  (dead after out-proj)
  float*  res1  = (float*)(ws + 64 * MB);    // 16 MB (x1 fp32 after LN1 in-place)
  __bf16* x1b   = (__bf16*)(ws + 80 * MB);   // 8 MB
  __bf16* hb    = (__bf16*)(ws + 32 * MB);   // 32 MB, aliases qkvb+ctxb (dead)
  float*  res2  = (float*)(ws + 0 * MB);     // 16 MB, aliases weights (dead)

  // bf16 casts
  f32_to_bf16<<<4096, 256, 0, stream>>>(x, xb, 4096 * 1024);
  f32_to_bf16<<<3072, 256, 0, stream>>>(w_qkv, wqkvb, 3072 * 1024);
  f32_to_bf16<<<1024, 256, 0, stream>>>(w_out, woutb, 1024 * 1024);
  f32_to_bf16<<<4096, 256, 0, stream>>>(w1, w1b, 4096 * 1024);
  f32_to_bf16<<<4096, 256, 0, stream>>>(w2, w2b, 1024 * 4096);

  // QKV projection -> scattered q/k/v (q pre-scaled by 0.125)
  gemm_bt<0><<<dim3(24, 32), 256, 0, stream>>>(xb, wqkvb, b_qkv, nullptr, nullptr,
                                               qkvb, 4096, 3072, 1024);
  // attention
  flash_attn<<<dim3(32, 32), 256, 0, stream>>>(qkvb, qkvb + 4194304,
                                               qkvb + 2 * 4194304, ctxb);
  // out projection + residual(x)
  gemm_bt<1><<<dim3(8, 32), 256, 0, stream>>>(ctxb, woutb, b_out, x, res1, nullptr,
                                              4096, 1024, 1024);
  // LN1 (in-place fp32 + bf16 copy)
  layernorm_k<1><<<4096, 256, 0, stream>>>(res1, g1, be1, res1, x1b);
  // FFN1 + exact GELU
  gemm_bt<2><<<dim3(32, 32), 256, 0, stream>>>(x1b, w1b, bf1, nullptr, nullptr, hb,
                                               4096, 4096, 1024);
  // FFN2 + residual(x1)
  gemm_bt<3><<<dim3(8, 32), 256, 0, stream>>>(hb, w2b, bf2, res1, res2, nullptr,
                                              4096, 1024, 4096);
  // LN2 -> output
  layernorm_k<0><<<4096, 256, 0, stream>>>(res2, g2, be2, out, nullptr);
}